// Round 4
// baseline (228.972 us; speedup 1.0000x reference)
//
#include <hip/hip_runtime.h>

#define SQ2F 0.70710678118654752440f

// Filter taps are compile-time constants (reference _filters() is deterministic;
// float literals round identically to np.float32). Zeros fold out of FMA chains.
static constexpr float H0O[5] = {-0.05f, 0.25f, 0.6f, 0.25f, -0.05f};
static constexpr float H1O[7] = {(float)(-3.0/280.0), (float)(3.0/56.0), (float)(73.0/280.0),
                                 (float)(-17.0/28.0), (float)(73.0/280.0), (float)(3.0/56.0),
                                 (float)(-3.0/280.0)};
static constexpr float H0A[10] = {0.03516384f, 0.0f, -0.08832942f, 0.23389032f, 0.76027237f,
                                  0.5875183f, 0.0f, -0.11430184f, 0.0f, 0.0f};
static constexpr float H0B[10] = {0.0f, 0.0f, -0.11430184f, 0.0f, 0.5875183f,
                                  0.76027237f, 0.23389032f, -0.08832942f, 0.0f, 0.03516384f};
static constexpr float H1A[10] = {0.0f, 0.0f, -0.11430184f, 0.0f, 0.5875183f,
                                  -0.76027237f, 0.23389032f, 0.08832942f, 0.0f, -0.03516384f};
static constexpr float H1B[10] = {-0.03516384f, 0.0f, 0.08832942f, 0.23389032f, -0.76027237f,
                                  0.5875183f, 0.0f, -0.11430184f, 0.0f, 0.0f};

__device__ __forceinline__ int symref(int t, int L) {
    if (t < 0) t = -1 - t;
    if (t >= L) t = 2 * L - 1 - t;
    return t;
}

// ---------------------------------------------------------------------------
// Fused levels 1+2. Block = 512 threads; covers x core rows [32ti,32ti+32),
// cols [64tj,64tj+64). Produces yh0 (16x32), yh1 (8x16), ll2 (16x32).
// LDS overlays (45.9 KB peak; 512 thr -> 3 blocks/CU = 24 waves/CU):
//   S[    0.. 4420) : Xs 52x85  -> later Ls 48x81
//   S[ 4420.. 8632) : Los 52x81 -> later Lo2/Hi2 48x33 each
//   S[ 8632..11472) : His 40x71
// Band stages are column-per-lane (stride-1 LDS, conflict-free) with the
// q2c column-pair combine done via __shfl_xor(1); even lane writes band k,
// odd lane band 5-k (same u,v computed by both -> no duplicated FLOPs).
// ---------------------------------------------------------------------------
#define XS(r,c)  S[(r)*85 + (c)]
#define LS(r,c)  S[(r)*81 + (c)]
#define LOS(r,c) S[4420 + (r)*81 + (c)]
#define LO2(r,c) S[4420 + (r)*33 + (c)]
#define HI2(r,c) S[6004 + (r)*33 + (c)]
#define HIS(r,c) S[8632 + (r)*71 + (c)]

__global__ __launch_bounds__(512) void dtcwt_l12(
    const float* __restrict__ x,
    float* __restrict__ yh0,
    float* __restrict__ yh1,
    float* __restrict__ ll2)
{
    __shared__ float S[11472];
    int tid = threadIdx.x, bx = blockIdx.x;
    int tj = bx & 3, ti = (bx >> 2) & 7, bc = bx >> 5;
    const int xr0 = 32 * ti - 10, xc0 = 64 * tj - 10;
    const float* xb = x + (size_t)bc * 65536;

    // ---- stage 0: load x region 52x84 (reflected)
    for (int p = tid; p < 52 * 84; p += 512) {
        int r = p / 84, c = p - r * 84;
        XS(r, c) = xb[symref(xr0 + r, 256) * 256 + symref(xc0 + c, 256)];
    }
    __syncthreads();

    // ---- stage 1: row filters. Los[r][c] = lo at (x row xr0+r, x col xc0+2+c)
    for (int p = tid; p < 4160; p += 512) {       // 52 x 80, r fastest (stride-85: cf-free)
        int r = p % 52, c = p / 52;
        float l = 0.f;
        #pragma unroll
        for (int t = 0; t < 5; t++) l += H0O[t] * XS(r, c + 4 - t);
        LOS(r, c) = l;
    }
    // His[r][c] = hi at (x row 32ti-3+r, x col 64tj-3+c)
    for (int p = tid; p < 2800; p += 512) {       // 40 x 70
        int r = p % 40, c = p / 40;
        float h = 0.f;
        #pragma unroll
        for (int t = 0; t < 7; t++) h += H1O[t] * XS(7 + r, c + 10 - t);
        HIS(r, c) = h;
    }
    __syncthreads();

    // ---- stage 2b: ll tile Ls[r][c] = ll(32ti-8+r, 64tj-8+c), 48x80 (overlays Xs)
    for (int p = tid; p < 3840; p += 512) {       // c fastest: stride-1
        int c = p % 80, r = p / 80;
        float v = 0.f;
        #pragma unroll
        for (int t = 0; t < 5; t++) v += H0O[t] * LOS(r + 4 - t, c);
        LS(r, c) = v;
    }
    // ---- stage 2a: yh0, column-per-lane. 1024 items = 16 oi x 64 cols.
    {
        float* yb = yh0 + (size_t)bc * 196608;
        const size_t bs = 32768;
        int lane = tid & 63;                      // = cc_full (x col pair index*2+cc)
        #pragma unroll
        for (int it = 0; it < 2; ++it) {
            int oi = (tid >> 6) + 8 * it;
            float low[8], hiw[8];
            #pragma unroll
            for (int k = 0; k < 8; k++) {
                low[k] = LOS(2 * oi + 7 + k, 8 + lane);   // row uniform, col=lane: cf-free
                hiw[k] = HIS(2 * oi + k,     3 + lane);
            }
            float lh_e = 0, lh_o = 0, hh_e = 0, hh_o = 0, hl_e = 0, hl_o = 0;
            #pragma unroll
            for (int t = 0; t < 7; t++) {
                lh_e += H1O[t] * low[6 - t]; lh_o += H1O[t] * low[7 - t];
                hh_e += H1O[t] * hiw[6 - t]; hh_o += H1O[t] * hiw[7 - t];
            }
            #pragma unroll
            for (int t = 0; t < 5; t++) {
                hl_e += H0O[t] * hiw[5 - t]; hl_o += H0O[t] * hiw[6 - t];
            }
            lh_e *= SQ2F; lh_o *= SQ2F; hh_e *= SQ2F; hh_o *= SQ2F; hl_e *= SQ2F; hl_o *= SQ2F;
            // partner column exchange; u = my_ev - other_od, v = other_ev + my_od
            float u_lh = lh_e - __shfl_xor(lh_o, 1), v_lh = __shfl_xor(lh_e, 1) + lh_o;
            float u_hh = hh_e - __shfl_xor(hh_o, 1), v_hh = __shfl_xor(hh_e, 1) + hh_o;
            float u_hl = hl_e - __shfl_xor(hl_o, 1), v_hl = __shfl_xor(hl_e, 1) + hl_o;
            int i0 = 16 * ti + oi, j0 = 32 * tj + (lane >> 1);
            size_t pix = ((size_t)i0 * 128 + j0) * 2;
            if ((lane & 1) == 0) {
                *(float2*)&yb[0 * bs + pix] = make_float2(u_lh, v_lh);
                *(float2*)&yb[1 * bs + pix] = make_float2(u_hh, v_hh);
                *(float2*)&yb[2 * bs + pix] = make_float2(u_hl, v_hl);
            } else {
                *(float2*)&yb[5 * bs + pix] = make_float2(v_lh, u_lh);
                *(float2*)&yb[4 * bs + pix] = make_float2(v_hh, u_hh);
                *(float2*)&yb[3 * bs + pix] = make_float2(v_hl, u_hl);
            }
        }
    }
    __syncthreads();

    // ---- stage 3: rowdfilt on Ls -> Lo2/Hi2 (48 rows x 16 n), overlays Los
    for (int p = tid; p < 768; p += 512) {        // r fastest (stride-81/33: cf-free)
        int r = p % 48, nl = p / 48;
        int gc = 64 * tj + 4 * nl - 8;
        float v[20];
        #pragma unroll
        for (int k = 0; k < 20; k++)
            v[k] = LS(r, symref(gc + k, 256) - 64 * tj + 8);
        float aLo = 0.f, bLo = 0.f, aHi = 0.f, bHi = 0.f;
        #pragma unroll
        for (int t = 0; t < 10; t++) {
            float vo = v[19 - 2 * t], ve = v[18 - 2 * t];
            aLo += H0B[t] * vo; bLo += H0A[t] * ve;
            aHi += H1B[t] * vo; bHi += H1A[t] * ve;
        }
        LO2(r, 2*nl)   = aLo;  // lowpass : ev=a, od=b
        LO2(r, 2*nl+1) = bLo;
        HI2(r, 2*nl)   = bHi;  // highpass: ev=b, od=a
        HI2(r, 2*nl+1) = aHi;
    }
    __syncthreads();

    // ---- stage 4: coldfilt x4 + q2c -> yh1, ll2. Column-per-lane, 256 items.
    if (tid < 256) {
        int c  = tid & 31;                        // LO2/HI2 column (stride-1: cf-free)
        int li = tid >> 5;                        // 0..7
        int i1 = 8 * ti + li;
        float vl[20], vh[20];
        #pragma unroll
        for (int k = 0; k < 20; k++) {
            int loc = symref(32 * ti + 4 * li - 8 + k, 256) - 32 * ti + 8;
            vl[k] = LO2(loc, c);
            vh[k] = HI2(loc, c);
        }
        float a_ll=0,b_ll=0,a_lh=0,b_lh=0,a_hl=0,b_hl=0,a_hh=0,b_hh=0;
        #pragma unroll
        for (int t = 0; t < 10; t++) {
            float vo_l = vl[19 - 2*t], ve_l = vl[18 - 2*t];
            float vo_h = vh[19 - 2*t], ve_h = vh[18 - 2*t];
            a_ll += H0B[t] * vo_l;  b_ll += H0A[t] * ve_l;
            a_lh += H1B[t] * vo_l;  b_lh += H1A[t] * ve_l;
            a_hl += H0B[t] * vo_h;  b_hl += H0A[t] * ve_h;
            a_hh += H1B[t] * vo_h;  b_hh += H1A[t] * ve_h;
        }
        // ll (lowpass: ev=a, od=b): column-granular direct write, coalesced
        float* llb = ll2 + (size_t)bc * 16384;
        int gcol = 32 * tj + c;
        llb[(size_t)(2*i1)   * 128 + gcol] = a_ll;
        llb[(size_t)(2*i1+1) * 128 + gcol] = b_ll;
        // bands: lh/hh highpass (ev=b, od=a), hl lowpass (ev=a, od=b)
        float lh_e = SQ2F*b_lh, lh_o = SQ2F*a_lh;
        float hh_e = SQ2F*b_hh, hh_o = SQ2F*a_hh;
        float hl_e = SQ2F*a_hl, hl_o = SQ2F*b_hl;
        float u_lh = lh_e - __shfl_xor(lh_o, 1), v_lh = __shfl_xor(lh_e, 1) + lh_o;
        float u_hh = hh_e - __shfl_xor(hh_o, 1), v_hh = __shfl_xor(hh_e, 1) + hh_o;
        float u_hl = hl_e - __shfl_xor(hl_o, 1), v_hl = __shfl_xor(hl_e, 1) + hl_o;
        float* yb = yh1 + (size_t)bc * 49152;
        int j1 = 16 * tj + (c >> 1);
        size_t pix = ((size_t)i1 * 64 + j1) * 2;
        const size_t bs = 8192;
        if ((c & 1) == 0) {
            *(float2*)&yb[0 * bs + pix] = make_float2(u_lh, v_lh);
            *(float2*)&yb[1 * bs + pix] = make_float2(u_hh, v_hh);
            *(float2*)&yb[2 * bs + pix] = make_float2(u_hl, v_hl);
        } else {
            *(float2*)&yb[5 * bs + pix] = make_float2(v_lh, u_lh);
            *(float2*)&yb[4 * bs + pix] = make_float2(v_hh, u_hh);
            *(float2*)&yb[3 * bs + pix] = make_float2(v_hl, u_hl);
        }
    }
}

// ---------------------------------------------------------------------------
// Level 3 (unchanged, proven): rowdfilt + coldfilt x4 + bands.
// ---------------------------------------------------------------------------
__global__ __launch_bounds__(256) void level_fused(
    const float* __restrict__ X,
    float* __restrict__ llout,
    float* __restrict__ yh,
    int R, int C, int nbi, int nbj)
{
    __shared__ float Xs[80][81];
    __shared__ float Lo[80][33];
    __shared__ float Hi[80][33];

    int tid = threadIdx.x;
    int bx  = blockIdx.x;
    int tj = bx % nbj; int ti = (bx / nbj) % nbi; int bc = bx / (nbj * nbi);
    int i0 = ti * 16, j0 = tj * 16;
    int gr0 = 4 * i0 - 8, gc0 = 4 * j0 - 8;
    const float* Xb = X + (size_t)bc * R * C;

    for (int p = tid; p < 80 * 80; p += 256) {
        int r = p / 80, c = p - r * 80;
        Xs[r][c] = Xb[(size_t)symref(gr0 + r, R) * C + symref(gc0 + c, C)];
    }
    __syncthreads();

    for (int p = tid; p < 80 * 16; p += 256) {
        int nl = p / 80, r = p - nl * 80;
        float v[20];
        #pragma unroll
        for (int k = 0; k < 20; k++) v[k] = Xs[r][4 * nl + k];
        float aLo = 0.f, bLo = 0.f, aHi = 0.f, bHi = 0.f;
        #pragma unroll
        for (int t = 0; t < 10; t++) {
            float vo = v[19 - 2 * t], ve = v[18 - 2 * t];
            aLo += H0B[t] * vo; bLo += H0A[t] * ve;
            aHi += H1B[t] * vo; bHi += H1A[t] * ve;
        }
        Lo[r][2*nl]   = aLo;
        Lo[r][2*nl+1] = bLo;
        Hi[r][2*nl]   = bHi;
        Hi[r][2*nl+1] = aHi;
    }
    __syncthreads();

    int R4 = R >> 2, Wq = C >> 2, C2 = C >> 1;
    int lj = tid & 15, li = tid >> 4;
    int i = i0 + li, j = j0 + lj;

    float ll_[2][2], lh_[2][2], hl_[2][2], hh_[2][2];
    #pragma unroll
    for (int cc = 0; cc < 2; cc++) {
        int c = 2 * lj + cc;
        float vl[20], vh[20];
        #pragma unroll
        for (int k = 0; k < 20; k++) {
            vl[k] = Lo[4 * li + k][c];
            vh[k] = Hi[4 * li + k][c];
        }
        float a_ll=0,b_ll=0,a_lh=0,b_lh=0,a_hl=0,b_hl=0,a_hh=0,b_hh=0;
        #pragma unroll
        for (int t = 0; t < 10; t++) {
            float vo_l = vl[19 - 2*t], ve_l = vl[18 - 2*t];
            float vo_h = vh[19 - 2*t], ve_h = vh[18 - 2*t];
            a_ll += H0B[t] * vo_l;  b_ll += H0A[t] * ve_l;
            a_lh += H1B[t] * vo_l;  b_lh += H1A[t] * ve_l;
            a_hl += H0B[t] * vo_h;  b_hl += H0A[t] * ve_h;
            a_hh += H1B[t] * vo_h;  b_hh += H1A[t] * ve_h;
        }
        ll_[0][cc] = a_ll; ll_[1][cc] = b_ll;
        lh_[0][cc] = b_lh; lh_[1][cc] = a_lh;
        hl_[0][cc] = a_hl; hl_[1][cc] = b_hl;
        hh_[0][cc] = b_hh; hh_[1][cc] = a_hh;
    }

    float* llb = llout + (size_t)bc * (R >> 1) * C2;
    llb[(size_t)(2*i)*C2   + 2*j]     = ll_[0][0];
    llb[(size_t)(2*i)*C2   + 2*j + 1] = ll_[0][1];
    llb[(size_t)(2*i+1)*C2 + 2*j]     = ll_[1][0];
    llb[(size_t)(2*i+1)*C2 + 2*j + 1] = ll_[1][1];

    float* yb = yh + (size_t)bc * 6 * R4 * Wq * 2;
    size_t pix = ((size_t)i * Wq + j) * 2;
    size_t bs  = (size_t)R4 * Wq * 2;
    {
        float a = SQ2F*lh_[0][0], b = SQ2F*lh_[0][1], c = SQ2F*lh_[1][0], d = SQ2F*lh_[1][1];
        yb[0*bs + pix] = a - d; yb[0*bs + pix + 1] = b + c;
        yb[5*bs + pix] = a + d; yb[5*bs + pix + 1] = b - c;
    }
    {
        float a = SQ2F*hh_[0][0], b = SQ2F*hh_[0][1], c = SQ2F*hh_[1][0], d = SQ2F*hh_[1][1];
        yb[1*bs + pix] = a - d; yb[1*bs + pix + 1] = b + c;
        yb[4*bs + pix] = a + d; yb[4*bs + pix + 1] = b - c;
    }
    {
        float a = SQ2F*hl_[0][0], b = SQ2F*hl_[0][1], c = SQ2F*hl_[1][0], d = SQ2F*hl_[1][1];
        yb[2*bs + pix] = a - d; yb[2*bs + pix + 1] = b + c;
        yb[3*bs + pix] = a + d; yb[3*bs + pix + 1] = b - c;
    }
}

extern "C" void kernel_launch(void* const* d_in, const int* in_sizes, int n_in,
                              void* d_out, int out_size, void* d_ws, size_t ws_size,
                              hipStream_t stream) {
    const float* x = (const float*)d_in[0];
    float* out = (float*)d_out;

    const int BC = 8 * 16;  // 128

    float* out_ll  = out;                        // 128*64*64
    float* out_yh0 = out + 524288;               // 128*6*128*128*2
    float* out_yh1 = out + 25690112;             // 128*6*64*64*2
    float* out_yh2 = out + 31981568;             // 128*6*32*32*2

    float* ll2 = (float*)d_ws;                   // 128*128*128 floats = 8 MiB

    // fused levels 1+2: x -> yh0, yh1, ll2
    dtcwt_l12<<<BC * 32, 512, 0, stream>>>(x, out_yh0, out_yh1, ll2);

    // level 3: ll2(128x128) -> yh2, final ll(64x64)
    level_fused<<<BC * 4, 256, 0, stream>>>(ll2, out_ll, out_yh2, 128, 128, 2, 2);
}

// Round 5
// 209.795 us; speedup vs baseline: 1.0914x; 1.0914x over previous
//
#include <hip/hip_runtime.h>

#define SQ2F 0.70710678118654752440f

// Filter taps are compile-time constants (reference _filters() is deterministic;
// float literals round identically to np.float32). Zeros fold out of FMA chains.
static constexpr float H0O[5] = {-0.05f, 0.25f, 0.6f, 0.25f, -0.05f};
static constexpr float H1O[7] = {(float)(-3.0/280.0), (float)(3.0/56.0), (float)(73.0/280.0),
                                 (float)(-17.0/28.0), (float)(73.0/280.0), (float)(3.0/56.0),
                                 (float)(-3.0/280.0)};
static constexpr float H0A[10] = {0.03516384f, 0.0f, -0.08832942f, 0.23389032f, 0.76027237f,
                                  0.5875183f, 0.0f, -0.11430184f, 0.0f, 0.0f};
static constexpr float H0B[10] = {0.0f, 0.0f, -0.11430184f, 0.0f, 0.5875183f,
                                  0.76027237f, 0.23389032f, -0.08832942f, 0.0f, 0.03516384f};
static constexpr float H1A[10] = {0.0f, 0.0f, -0.11430184f, 0.0f, 0.5875183f,
                                  -0.76027237f, 0.23389032f, 0.08832942f, 0.0f, -0.03516384f};
static constexpr float H1B[10] = {-0.03516384f, 0.0f, 0.08832942f, 0.23389032f, -0.76027237f,
                                  0.5875183f, 0.0f, -0.11430184f, 0.0f, 0.0f};

__device__ __forceinline__ int symref(int t, int L) {
    if (t < 0) t = -1 - t;
    if (t >= L) t = 2 * L - 1 - t;
    return t;
}

// async global->LDS, 4 B per lane; lds dest must be wave-uniform base (+lane*4)
__device__ __forceinline__ void gload_lds4(const float* g, float* lds) {
    __builtin_amdgcn_global_load_lds(
        (const __attribute__((address_space(1))) void*)g,
        (__attribute__((address_space(3))) void*)lds, 4, 0, 0);
}

// ---------------------------------------------------------------------------
// Fused levels 1+2. Block = 512 threads; covers x core rows [32ti,32ti+32),
// cols [64tj,64tj+64). Produces yh0 (16x32), yh1 (8x16), ll2 (16x32).
// LDS overlays (43.9 KB -> 3 blocks/CU):
//   S[    0.. 4368) : Xs 52x84 (pitch 84, contiguous for global_load_lds)
//                     -> after stage 1, reused as Ls 48 x pitch-85 (odd pitch
//                        so stage-3's lane-varies-row reads are conflict-free)
//   S[ 4368.. 8528) : Los 52x80 -> after stage 2, LO2/HI2 48x33 each
//   S[ 8528..10960) : His 38x64
// All hot LDS reads are lane-stride-1 (row uniform per instruction) or
// odd-pitch lane-varies-row => <=2 lanes/bank (free per m136).
// ---------------------------------------------------------------------------
#define XS(r,c)  S[(r)*84 + (c)]
#define LS(r,c)  S[(r)*85 + (c)]
#define LOS(r,c) S[4368 + (r)*80 + (c)]
#define LO2(r,c) S[4368 + (r)*33 + (c)]
#define HI2(r,c) S[5952 + (r)*33 + (c)]
#define HIS(r,c) S[8528 + (r)*64 + (c)]

__global__ __launch_bounds__(512) void dtcwt_l12(
    const float* __restrict__ x,
    float* __restrict__ yh0,
    float* __restrict__ yh1,
    float* __restrict__ ll2)
{
    __shared__ float S[10960];
    int tid = threadIdx.x, bx = blockIdx.x;
    int tj = bx & 3, ti = (bx >> 2) & 7, bc = bx >> 5;
    const int xr0 = 32 * ti - 10, xc0 = 64 * tj - 10;
    const float* xb = x + (size_t)bc * 65536;
    const int lane = tid & 63;

    // ---- stage 0: async DMA of 52x84 x-region into Xs (contiguous, pitch 84)
    const bool interior0 = (ti >= 1) && (ti <= 6) && (tj >= 1) && (tj <= 2);
    if (interior0) {
        for (int p = tid; p < 4368; p += 512) {
            int r = p / 84, c = p - r * 84;
            gload_lds4(xb + (xr0 + r) * 256 + (xc0 + c), &S[p - lane]);
        }
    } else {
        for (int p = tid; p < 4368; p += 512) {
            int r = p / 84, c = p - r * 84;
            gload_lds4(xb + symref(xr0 + r, 256) * 256 + symref(xc0 + c, 256),
                       &S[p - lane]);
        }
    }
    __syncthreads();   // drains vmcnt for the DMA

    // ---- stage 1: row filters (lanes stride-1 in c)
    // Los(r,c) = lo(xr0+r, 64tj-8+c) = sum_t H0O[t]*XS(r, c+4-t)
    for (int p = tid; p < 4160; p += 512) {       // 52 x 80
        int r = p / 80, c = p - r * 80;
        float l = 0.f;
        #pragma unroll
        for (int t = 0; t < 5; t++) l += H0O[t] * XS(r, c + 4 - t);
        LOS(r, c) = l;
    }
    // His(r,c) = hi(32ti-3+r, 64tj+c) = sum_t H1O[t]*XS(r+7, c+13-t)
    for (int p = tid; p < 2432; p += 512) {       // 38 x 64
        int r = p >> 6, c = p & 63;
        float h = 0.f;
        #pragma unroll
        for (int t = 0; t < 7; t++) h += H1O[t] * XS(r + 7, c + 13 - t);
        HIS(r, c) = h;
    }
    __syncthreads();

    // ---- stage 2b: ll tile Ls(r,c) = ll(32ti-8+r, 64tj-8+c)  (pitch 85, over Xs)
    for (int p = tid; p < 3840; p += 512) {       // 48 x 80, lanes stride-1
        int r = p / 80, c = p - r * 80;
        float v = 0.f;
        #pragma unroll
        for (int t = 0; t < 5; t++) v += H0O[t] * LOS(r + 4 - t, c);
        LS(r, c) = v;
    }
    // ---- stage 2a: yh0, column-per-lane (lanes stride-1), merged band stores
    {
        float* yb = yh0 + (size_t)bc * 196608;
        const size_t bs = 32768;
        int par = lane & 1;
        #pragma unroll
        for (int it = 0; it < 2; ++it) {
            int oi = (tid >> 6) + 8 * it;
            float low[8], hiw[8];
            #pragma unroll
            for (int k = 0; k < 8; k++) {
                low[k] = LOS(2 * oi + 7 + k, lane + 8);
                hiw[k] = HIS(2 * oi + k,     lane);
            }
            float lh_e = 0, lh_o = 0, hh_e = 0, hh_o = 0, hl_e = 0, hl_o = 0;
            #pragma unroll
            for (int t = 0; t < 7; t++) {
                lh_e += H1O[t] * low[6 - t]; lh_o += H1O[t] * low[7 - t];
                hh_e += H1O[t] * hiw[6 - t]; hh_o += H1O[t] * hiw[7 - t];
            }
            #pragma unroll
            for (int t = 0; t < 5; t++) {
                hl_e += H0O[t] * hiw[5 - t]; hl_o += H0O[t] * hiw[6 - t];
            }
            lh_e *= SQ2F; lh_o *= SQ2F; hh_e *= SQ2F; hh_o *= SQ2F; hl_e *= SQ2F; hl_o *= SQ2F;
            // p = ev - shfl(od) ; q = shfl(ev) + od
            // even lane: (p,q) -> band k ; odd lane: (q,p) -> band 5-k
            float p0 = lh_e - __shfl_xor(lh_o, 1), q0 = __shfl_xor(lh_e, 1) + lh_o;
            float p1 = hh_e - __shfl_xor(hh_o, 1), q1 = __shfl_xor(hh_e, 1) + hh_o;
            float p2 = hl_e - __shfl_xor(hl_o, 1), q2 = __shfl_xor(hl_e, 1) + hl_o;
            int i0 = 16 * ti + oi, j0 = 32 * tj + (lane >> 1);
            size_t pix = ((size_t)i0 * 128 + j0) * 2;
            *(float2*)&yb[(size_t)(par ? 5 : 0) * bs + pix] =
                par ? make_float2(q0, p0) : make_float2(p0, q0);
            *(float2*)&yb[(size_t)(par ? 4 : 1) * bs + pix] =
                par ? make_float2(q1, p1) : make_float2(p1, q1);
            *(float2*)&yb[(size_t)(par ? 3 : 2) * bs + pix] =
                par ? make_float2(q2, p2) : make_float2(p2, q2);
        }
    }
    __syncthreads();

    // ---- stage 3: rowdfilt on Ls -> LO2/HI2 (48 rows x 16 n), over Los region
    {
        const bool interiorC = (tj >= 1) && (tj <= 2);
        for (int p = tid; p < 768; p += 512) {    // lanes vary r: stride-85, cf-free
            int r = p % 48, nl = p / 48;
            float v[20];
            if (interiorC) {
                #pragma unroll
                for (int k = 0; k < 20; k++) v[k] = LS(r, 4 * nl + k);
            } else {
                int gcb = 64 * tj + 4 * nl - 8;
                #pragma unroll
                for (int k = 0; k < 20; k++)
                    v[k] = LS(r, symref(gcb + k, 256) - 64 * tj + 8);
            }
            float aLo = 0.f, bLo = 0.f, aHi = 0.f, bHi = 0.f;
            #pragma unroll
            for (int t = 0; t < 10; t++) {
                float vo = v[19 - 2 * t], ve = v[18 - 2 * t];
                aLo += H0B[t] * vo; bLo += H0A[t] * ve;
                aHi += H1B[t] * vo; bHi += H1A[t] * ve;
            }
            LO2(r, 2*nl)   = aLo;  // lowpass : ev=a, od=b
            LO2(r, 2*nl+1) = bLo;
            HI2(r, 2*nl)   = bHi;  // highpass: ev=b, od=a
            HI2(r, 2*nl+1) = aHi;
        }
    }
    __syncthreads();

    // ---- stage 4: coldfilt x4 + q2c -> yh1, ll2. Column-per-lane, 256 items.
    if (tid < 256) {
        int c  = tid & 31;                        // stride-1 within half-wave: cf-free
        int li = tid >> 5;                        // 0..7
        int i1 = 8 * ti + li;
        float vl[20], vh[20];
        const bool interiorR = (ti >= 1) && (ti <= 6);
        if (interiorR) {
            #pragma unroll
            for (int k = 0; k < 20; k++) {
                vl[k] = LO2(4 * li + k, c);
                vh[k] = HI2(4 * li + k, c);
            }
        } else {
            #pragma unroll
            for (int k = 0; k < 20; k++) {
                int loc = symref(32 * ti + 4 * li - 8 + k, 256) - 32 * ti + 8;
                vl[k] = LO2(loc, c);
                vh[k] = HI2(loc, c);
            }
        }
        float a_ll=0,b_ll=0,a_lh=0,b_lh=0,a_hl=0,b_hl=0,a_hh=0,b_hh=0;
        #pragma unroll
        for (int t = 0; t < 10; t++) {
            float vo_l = vl[19 - 2*t], ve_l = vl[18 - 2*t];
            float vo_h = vh[19 - 2*t], ve_h = vh[18 - 2*t];
            a_ll += H0B[t] * vo_l;  b_ll += H0A[t] * ve_l;
            a_lh += H1B[t] * vo_l;  b_lh += H1A[t] * ve_l;
            a_hl += H0B[t] * vo_h;  b_hl += H0A[t] * ve_h;
            a_hh += H1B[t] * vo_h;  b_hh += H1A[t] * ve_h;
        }
        // ll2 (lowpass: ev=a, od=b), coalesced column writes
        float* llb = ll2 + (size_t)bc * 16384;
        int gcol = 32 * tj + c;
        llb[(size_t)(2*i1)   * 128 + gcol] = a_ll;
        llb[(size_t)(2*i1+1) * 128 + gcol] = b_ll;
        // bands: lh/hh highpass (ev=b, od=a), hl lowpass (ev=a, od=b)
        float lh_e = SQ2F*b_lh, lh_o = SQ2F*a_lh;
        float hh_e = SQ2F*b_hh, hh_o = SQ2F*a_hh;
        float hl_e = SQ2F*a_hl, hl_o = SQ2F*b_hl;
        int par = c & 1;
        float p0 = lh_e - __shfl_xor(lh_o, 1), q0 = __shfl_xor(lh_e, 1) + lh_o;
        float p1 = hh_e - __shfl_xor(hh_o, 1), q1 = __shfl_xor(hh_e, 1) + hh_o;
        float p2 = hl_e - __shfl_xor(hl_o, 1), q2 = __shfl_xor(hl_e, 1) + hl_o;
        float* yb = yh1 + (size_t)bc * 49152;
        int j1 = 16 * tj + (c >> 1);
        size_t pix = ((size_t)i1 * 64 + j1) * 2;
        const size_t bs = 8192;
        *(float2*)&yb[(size_t)(par ? 5 : 0) * bs + pix] =
            par ? make_float2(q0, p0) : make_float2(p0, q0);
        *(float2*)&yb[(size_t)(par ? 4 : 1) * bs + pix] =
            par ? make_float2(q1, p1) : make_float2(p1, q1);
        *(float2*)&yb[(size_t)(par ? 3 : 2) * bs + pix] =
            par ? make_float2(q2, p2) : make_float2(p2, q2);
    }
}

// ---------------------------------------------------------------------------
// Level 3 (unchanged, proven): rowdfilt + coldfilt x4 + bands.
// ---------------------------------------------------------------------------
__global__ __launch_bounds__(256) void level_fused(
    const float* __restrict__ X,
    float* __restrict__ llout,
    float* __restrict__ yh,
    int R, int C, int nbi, int nbj)
{
    __shared__ float Xs[80][81];
    __shared__ float Lo[80][33];
    __shared__ float Hi[80][33];

    int tid = threadIdx.x;
    int bx  = blockIdx.x;
    int tj = bx % nbj; int ti = (bx / nbj) % nbi; int bc = bx / (nbj * nbi);
    int i0 = ti * 16, j0 = tj * 16;
    int gr0 = 4 * i0 - 8, gc0 = 4 * j0 - 8;
    const float* Xb = X + (size_t)bc * R * C;

    for (int p = tid; p < 80 * 80; p += 256) {
        int r = p / 80, c = p - r * 80;
        Xs[r][c] = Xb[(size_t)symref(gr0 + r, R) * C + symref(gc0 + c, C)];
    }
    __syncthreads();

    for (int p = tid; p < 80 * 16; p += 256) {
        int nl = p / 80, r = p - nl * 80;
        float v[20];
        #pragma unroll
        for (int k = 0; k < 20; k++) v[k] = Xs[r][4 * nl + k];
        float aLo = 0.f, bLo = 0.f, aHi = 0.f, bHi = 0.f;
        #pragma unroll
        for (int t = 0; t < 10; t++) {
            float vo = v[19 - 2 * t], ve = v[18 - 2 * t];
            aLo += H0B[t] * vo; bLo += H0A[t] * ve;
            aHi += H1B[t] * vo; bHi += H1A[t] * ve;
        }
        Lo[r][2*nl]   = aLo;
        Lo[r][2*nl+1] = bLo;
        Hi[r][2*nl]   = bHi;
        Hi[r][2*nl+1] = aHi;
    }
    __syncthreads();

    int R4 = R >> 2, Wq = C >> 2, C2 = C >> 1;
    int lj = tid & 15, li = tid >> 4;
    int i = i0 + li, j = j0 + lj;

    float ll_[2][2], lh_[2][2], hl_[2][2], hh_[2][2];
    #pragma unroll
    for (int cc = 0; cc < 2; cc++) {
        int c = 2 * lj + cc;
        float vl[20], vh[20];
        #pragma unroll
        for (int k = 0; k < 20; k++) {
            vl[k] = Lo[4 * li + k][c];
            vh[k] = Hi[4 * li + k][c];
        }
        float a_ll=0,b_ll=0,a_lh=0,b_lh=0,a_hl=0,b_hl=0,a_hh=0,b_hh=0;
        #pragma unroll
        for (int t = 0; t < 10; t++) {
            float vo_l = vl[19 - 2*t], ve_l = vl[18 - 2*t];
            float vo_h = vh[19 - 2*t], ve_h = vh[18 - 2*t];
            a_ll += H0B[t] * vo_l;  b_ll += H0A[t] * ve_l;
            a_lh += H1B[t] * vo_l;  b_lh += H1A[t] * ve_l;
            a_hl += H0B[t] * vo_h;  b_hl += H0A[t] * ve_h;
            a_hh += H1B[t] * vo_h;  b_hh += H1A[t] * ve_h;
        }
        ll_[0][cc] = a_ll; ll_[1][cc] = b_ll;
        lh_[0][cc] = b_lh; lh_[1][cc] = a_lh;
        hl_[0][cc] = a_hl; hl_[1][cc] = b_hl;
        hh_[0][cc] = b_hh; hh_[1][cc] = a_hh;
    }

    float* llb = llout + (size_t)bc * (R >> 1) * C2;
    llb[(size_t)(2*i)*C2   + 2*j]     = ll_[0][0];
    llb[(size_t)(2*i)*C2   + 2*j + 1] = ll_[0][1];
    llb[(size_t)(2*i+1)*C2 + 2*j]     = ll_[1][0];
    llb[(size_t)(2*i+1)*C2 + 2*j + 1] = ll_[1][1];

    float* yb = yh + (size_t)bc * 6 * R4 * Wq * 2;
    size_t pix = ((size_t)i * Wq + j) * 2;
    size_t bs  = (size_t)R4 * Wq * 2;
    {
        float a = SQ2F*lh_[0][0], b = SQ2F*lh_[0][1], c = SQ2F*lh_[1][0], d = SQ2F*lh_[1][1];
        yb[0*bs + pix] = a - d; yb[0*bs + pix + 1] = b + c;
        yb[5*bs + pix] = a + d; yb[5*bs + pix + 1] = b - c;
    }
    {
        float a = SQ2F*hh_[0][0], b = SQ2F*hh_[0][1], c = SQ2F*hh_[1][0], d = SQ2F*hh_[1][1];
        yb[1*bs + pix] = a - d; yb[1*bs + pix + 1] = b + c;
        yb[4*bs + pix] = a + d; yb[4*bs + pix + 1] = b - c;
    }
    {
        float a = SQ2F*hl_[0][0], b = SQ2F*hl_[0][1], c = SQ2F*hl_[1][0], d = SQ2F*hl_[1][1];
        yb[2*bs + pix] = a - d; yb[2*bs + pix + 1] = b + c;
        yb[3*bs + pix] = a + d; yb[3*bs + pix + 1] = b - c;
    }
}

extern "C" void kernel_launch(void* const* d_in, const int* in_sizes, int n_in,
                              void* d_out, int out_size, void* d_ws, size_t ws_size,
                              hipStream_t stream) {
    const float* x = (const float*)d_in[0];
    float* out = (float*)d_out;

    const int BC = 8 * 16;  // 128

    float* out_ll  = out;                        // 128*64*64
    float* out_yh0 = out + 524288;               // 128*6*128*128*2
    float* out_yh1 = out + 25690112;             // 128*6*64*64*2
    float* out_yh2 = out + 31981568;             // 128*6*32*32*2

    float* ll2 = (float*)d_ws;                   // 128*128*128 floats = 8 MiB

    // fused levels 1+2: x -> yh0, yh1, ll2
    dtcwt_l12<<<BC * 32, 512, 0, stream>>>(x, out_yh0, out_yh1, ll2);

    // level 3: ll2(128x128) -> yh2, final ll(64x64)
    level_fused<<<BC * 4, 256, 0, stream>>>(ll2, out_ll, out_yh2, 128, 128, 2, 2);
}